// Round 11
// baseline (149.330 us; speedup 1.0000x reference)
//
#include <hip/hip_runtime.h>
#include <hip/hip_bf16.h>
#include <stdint.h>

#define NB 4
#define NT 4096
#define NE 100
#define ND 64

typedef __attribute__((ext_vector_type(8))) short short8;
typedef __attribute__((ext_vector_type(4))) short short4_;
typedef __attribute__((ext_vector_type(4))) float float4_;
typedef unsigned short ushort_t;

__device__ __forceinline__ unsigned short f2bf(float f) {
  union { float f; uint32_t u; } v; v.f = f;
  uint32_t u = v.u;
  u += 0x7fffu + ((u >> 16) & 1u);   // RNE
  return (unsigned short)(u >> 16);
}

__device__ __forceinline__ float bf2f(short us) {
  union { uint32_t u; float f; } v;
  v.u = ((uint32_t)(unsigned short)us) << 16;
  return v.f;
}

__device__ __forceinline__ float fast_exp2(float x) {
#if __has_builtin(__builtin_amdgcn_exp2f)
  return __builtin_amdgcn_exp2f(x);
#else
  return exp2f(x);
#endif
}

// pack two f32 -> one u32 of 2 bf16 (low = a, high = b), single VALU op
__device__ __forceinline__ uint32_t cvtpk_bf16(float a, float b) {
  uint32_t r;
  asm("v_cvt_pk_bf16_f32 %0, %1, %2" : "=v"(r) : "v"(a), "v"(b));
  return r;
}

// ---------------- projection ----------------
// 256 blocks x 256 thr, 64 rows/block. q = (x@Wq)*0.125*log2e, k = x@Wk.
// V written in FRAGMENT-PACKED layout: Vp[b][tile][d][seg], 16B unit = 8
// consecutive kv for one d -> attn V-fragment loads are line-dense.
__global__ __launch_bounds__(256) void proj_kernel(
    const float* __restrict__ x, const float* __restrict__ Wq,
    const float* __restrict__ Wk, const float* __restrict__ Wv,
    ushort_t* __restrict__ Qb, ushort_t* __restrict__ Kb,
    ushort_t* __restrict__ Vp) {
  __shared__ __align__(16) float xs[64 * NE];          // 25.6 KB
  __shared__ __align__(16) ushort_t Wl[3][25][64][4];  // 38.4 KB
  __shared__ __align__(16) ushort_t Vl[64][72];        // 9.2 KB

  const int tid = threadIdx.x;
  const int r0  = blockIdx.x * 64;

  { // stage x[64][100] -> LDS, coalesced
    const float4_* xsrc = (const float4_*)(x + (size_t)r0 * NE);
    float4_* xdst = (float4_*)xs;
    for (int i = tid; i < 1600; i += 256) xdst[i] = xsrc[i];
  }
  { // stage W[3][100][64] -> LDS bf16, e-quad-major
    const int ch = tid >> 6, d = tid & 63;
    if (ch < 3) {
      const float* Ws = (ch == 0) ? Wq : (ch == 1) ? Wk : Wv;
      #pragma unroll 5
      for (int qd = 0; qd < 25; ++qd) {
        short4_ pk;
        #pragma unroll
        for (int jj = 0; jj < 4; ++jj)
          pk[jj] = (short)f2bf(Ws[(4*qd + jj)*ND + d]);
        *(short4_*)&Wl[ch][qd][d][0] = pk;
      }
    }
  }
  __syncthreads();

  const int wv = tid >> 6, lane = tid & 63;
  const float QS = 0.125f * 1.44269504088896340736f; // scale * log2(e)

  for (int it = 0; it < 4; ++it) {
    float aq[4] = {0,0,0,0}, ak[4] = {0,0,0,0}, av[4] = {0,0,0,0};
    const float* xw = xs + (it*16 + wv*4) * NE;
    for (int qd = 0; qd < 25; ++qd) {
      short4_ w4q = *(const short4_*)&Wl[0][qd][lane][0];
      short4_ w4k = *(const short4_*)&Wl[1][qd][lane][0];
      short4_ w4v = *(const short4_*)&Wl[2][qd][lane][0];
      float4_ x0 = *(const float4_*)&xw[0*NE + 4*qd];
      float4_ x1 = *(const float4_*)&xw[1*NE + 4*qd];
      float4_ x2 = *(const float4_*)&xw[2*NE + 4*qd];
      float4_ x3 = *(const float4_*)&xw[3*NE + 4*qd];
      #pragma unroll
      for (int jj = 0; jj < 4; ++jj) {
        float fq = bf2f(w4q[jj]), fk = bf2f(w4k[jj]), fv = bf2f(w4v[jj]);
        aq[0] += x0[jj]*fq; ak[0] += x0[jj]*fk; av[0] += x0[jj]*fv;
        aq[1] += x1[jj]*fq; ak[1] += x1[jj]*fk; av[1] += x1[jj]*fv;
        aq[2] += x2[jj]*fq; ak[2] += x2[jj]*fk; av[2] += x2[jj]*fv;
        aq[3] += x3[jj]*fq; ak[3] += x3[jj]*fk; av[3] += x3[jj]*fv;
      }
    }
    #pragma unroll
    for (int j = 0; j < 4; ++j) {
      int lrow = it*16 + wv*4 + j;
      int row  = r0 + lrow;
      Qb[(size_t)row*ND + lane] = f2bf(aq[j] * QS);
      Kb[(size_t)row*ND + lane] = f2bf(ak[j]);
      Vl[lrow][lane] = f2bf(av[j]);
    }
  }
  __syncthreads();

  { // fragment-packed V write: unit (t, d, seg) at t*4096 + d*64 + seg*8
    const int b = r0 >> 12, r0t = r0 & (NT - 1);
    ushort_t* Vdst = Vp + (size_t)b*NT*ND + (size_t)(r0t >> 6)*4096;
    for (int i = tid; i < 512; i += 256) {
      int d = i >> 3, seg = i & 7;
      short8 pk;
      #pragma unroll
      for (int k2 = 0; k2 < 8; ++k2) pk[k2] = (short)Vl[seg*8 + k2][d];
      *(short8*)(Vdst + d*64 + seg*8) = pk;
    }
  }
}

// ---------------- causal flash attention ----------------
// 512 blocks x 512 thr (8 waves = 4 kv-slots x 2 q-halves), 2 blocks/CU,
// XCD-mapped (blk&7=xcd, batch=xcd>>1 -> K/Vp L2-resident). Block = ONE
// 32-row q-group; heavy/light groups interleaved so co-resident blocks
// tend to sum to ~65 tiles. NO LDS staging, NO main-loop barriers: K and
// packed-V fragments load direct from L2-hot global, line-dense. VALU-lean
// softmax: defer-max (THR=8), per-lane partial lsum, cvt_pk bf16 packing.
// 4 kv-slot partials combined in-LDS once at the end.
__global__ __launch_bounds__(512, 4) void attn_kernel(
    const ushort_t* __restrict__ Qb, const ushort_t* __restrict__ Kb,
    const ushort_t* __restrict__ Vp, float* __restrict__ out) {
  __shared__ __align__(16) ushort_t Pb[8][16][72];   // 18.4 KB
  __shared__ __align__(16) float Om[8][16][64];      // 32 KB
  __shared__ float Ml[8][16][2];                     // 1 KB

  const int tid  = threadIdx.x;
  const int w    = tid >> 6, lane = tid & 63;
  const int pp   = w >> 1, h = w & 1;
  const int qrow = lane & 15, grp = lane >> 4;

  const int blk = blockIdx.x;
  const int xcd = blk & 7;
  const int b   = xcd >> 1;
  const int par = xcd & 1;
  const int u   = blk >> 3;                      // 0..63 per XCD
  // heavy groups (u<32) descending, light (u>=32) ascending: co-resident
  // pairs (u, u+32) sum to ~65 tiles if dispatch sweeps CUs twice.
  const int g = (u < 32) ? (127 - (2*u + par)) : ((u - 32)*2 + par);

  const int q0 = g << 5;
  const int nt = (g >> 1) + 1;
  const int qglob = q0 + h*16 + qrow;

  const ushort_t* Kbase = Kb + (size_t)b*NT*ND;
  const ushort_t* Vpb   = Vp + (size_t)b*NT*ND;
  ushort_t* Pw = &Pb[w][0][0];

  const ushort_t* Qr = Qb + ((size_t)(b*NT + q0 + h*16 + qrow))*ND + 8*grp;
  const short8 qf0 = *(const short8*)(Qr);
  const short8 qf1 = *(const short8*)(Qr + 32);

  float4_ O0 = {0,0,0,0}, O1 = {0,0,0,0}, O2 = {0,0,0,0}, O3 = {0,0,0,0};
  float m = -1e30f, lsum = 0.f;    // lsum = per-lane partial row sum

  for (int t = pp; t < nt; t += 4) {
    const int kv0 = t << 6;

    // K fragments direct from global (L2-hot; 64B-dense per row, L1 catches
    // the complementary half via the +32 load)
    short8 kc[8];
    #pragma unroll
    for (int st = 0; st < 4; ++st) {
      const ushort_t* kp = Kbase + (size_t)(kv0 + st*16 + qrow)*ND + 8*grp;
      kc[2*st]   = *(const short8*)(kp);
      kc[2*st+1] = *(const short8*)(kp + 32);
    }

    // S^T = K_tile . Q^T  (lane owns q-row qglob; kv = kv0+st*16+grp*4+r)
    float4_ sA[4];
    #pragma unroll
    for (int st = 0; st < 4; ++st) {
      float4_ acc = {0,0,0,0};
      acc = __builtin_amdgcn_mfma_f32_16x16x32_bf16(kc[2*st],   qf0, acc, 0,0,0);
      acc = __builtin_amdgcn_mfma_f32_16x16x32_bf16(kc[2*st+1], qf1, acc, 0,0,0);
      sA[st] = acc;
    }

    if (t == nt - 1) { // only the diagonal tile violates causality
      #pragma unroll
      for (int st = 0; st < 4; ++st)
        #pragma unroll
        for (int r = 0; r < 4; ++r) {
          int kv = kv0 + st*16 + grp*4 + r;
          if (kv > qglob) sA[st][r] = -1e30f;
        }
    }

    // online softmax (log2 domain), defer-max THR=8
    float pmax = sA[0][0];
    #pragma unroll
    for (int st = 0; st < 4; ++st)
      #pragma unroll
      for (int r = 0; r < 4; ++r) pmax = fmaxf(pmax, sA[st][r]);
    if (!__all(pmax <= m + 8.0f)) {
      float tm = pmax;
      tm = fmaxf(tm, __shfl_xor(tm, 16));
      tm = fmaxf(tm, __shfl_xor(tm, 32));
      const float mnew  = fmaxf(m, tm);
      const float alpha = fast_exp2(m - mnew);
      m = mnew;
      lsum *= alpha;
      #pragma unroll
      for (int r = 0; r < 4; ++r) {
        float ar = __shfl(alpha, grp*4 + r);
        O0[r] *= ar; O1[r] *= ar; O2[r] *= ar; O3[r] *= ar;
      }
    }

    // exp2 + packed bf16 P-write (cvt_pk: 1 VALU op per 2 values)
    #pragma unroll
    for (int st = 0; st < 4; ++st) {
      float pe0 = fast_exp2(sA[st][0] - m);
      float pe1 = fast_exp2(sA[st][1] - m);
      float pe2 = fast_exp2(sA[st][2] - m);
      float pe3 = fast_exp2(sA[st][3] - m);
      lsum += (pe0 + pe1) + (pe2 + pe3);
      uint2 pk;
      pk.x = cvtpk_bf16(pe0, pe1);
      pk.y = cvtpk_bf16(pe2, pe3);
      *(uint2*)&Pw[qrow*72 + st*16 + grp*4] = pk;
    }

    // V fragments (packed layout: line-dense), issued before the P readback
    short8 vf[8];
    #pragma unroll
    for (int j = 0; j < 4; ++j) {
      const ushort_t* vp = Vpb + (size_t)t*4096 + (j*16 + qrow)*64 + grp*8;
      vf[2*j]   = *(const short8*)(vp);
      vf[2*j+1] = *(const short8*)(vp + 32);
    }

    asm volatile("s_waitcnt lgkmcnt(0)" ::: "memory");

    const short8 pf0 = *(const short8*)&Pw[qrow*72 + 8*grp];
    const short8 pf1 = *(const short8*)&Pw[qrow*72 + 32 + 8*grp];
    O0 = __builtin_amdgcn_mfma_f32_16x16x32_bf16(pf0, vf[0], O0, 0,0,0);
    O0 = __builtin_amdgcn_mfma_f32_16x16x32_bf16(pf1, vf[1], O0, 0,0,0);
    O1 = __builtin_amdgcn_mfma_f32_16x16x32_bf16(pf0, vf[2], O1, 0,0,0);
    O1 = __builtin_amdgcn_mfma_f32_16x16x32_bf16(pf1, vf[3], O1, 0,0,0);
    O2 = __builtin_amdgcn_mfma_f32_16x16x32_bf16(pf0, vf[4], O2, 0,0,0);
    O2 = __builtin_amdgcn_mfma_f32_16x16x32_bf16(pf1, vf[5], O2, 0,0,0);
    O3 = __builtin_amdgcn_mfma_f32_16x16x32_bf16(pf0, vf[6], O3, 0,0,0);
    O3 = __builtin_amdgcn_mfma_f32_16x16x32_bf16(pf1, vf[7], O3, 0,0,0);
  }

  // finalize per-lane partial lsum -> per-row sum
  lsum += __shfl_xor(lsum, 16);
  lsum += __shfl_xor(lsum, 32);

  // ---- per-wave partials (O rows are grp*4+r; cols j*16+qrow)
  #pragma unroll
  for (int r = 0; r < 4; ++r) {
    int row = grp*4 + r;
    Om[w][row][0*16 + qrow] = O0[r];
    Om[w][row][1*16 + qrow] = O1[r];
    Om[w][row][2*16 + qrow] = O2[r];
    Om[w][row][3*16 + qrow] = O3[r];
  }
  if (lane < 16) {
    Ml[w][lane][0] = m;
    Ml[w][lane][1] = lsum;
  }
  __syncthreads();

  // ---- combine the 4 kv-slot partials per q-half, normalize, store
  for (int i = tid; i < 2048; i += 512) {
    int row = i >> 6, d = i & 63;
    int hh = row >> 4, r16 = row & 15;
    float M = -3e30f;
    #pragma unroll
    for (int p2 = 0; p2 < 4; ++p2)
      M = fmaxf(M, Ml[2*p2 + hh][r16][0]);
    float ls = 0.f, os = 0.f;
    #pragma unroll
    for (int p2 = 0; p2 < 4; ++p2) {
      int w2 = 2*p2 + hh;
      float sc = fast_exp2(Ml[w2][r16][0] - M);
      ls += sc * Ml[w2][r16][1];
      os += sc * Om[w2][r16][d];
    }
    out[((size_t)b*NT + q0 + row)*ND + d] = os / ls;
  }
}

extern "C" void kernel_launch(void* const* d_in, const int* in_sizes, int n_in,
                              void* d_out, int out_size, void* d_ws, size_t ws_size,
                              hipStream_t stream) {
  const float* x  = (const float*)d_in[0];
  const float* Wq = (const float*)d_in[1];
  const float* Wk = (const float*)d_in[2];
  const float* Wv = (const float*)d_in[3];
  float* out = (float*)d_out;

  ushort_t* Qb = (ushort_t*)d_ws;                 // [B][T][64] bf16, 2 MB
  ushort_t* Kb = Qb + (size_t)NB*NT*ND;           // [B][T][64] bf16, 2 MB
  ushort_t* Vp = Kb + (size_t)NB*NT*ND;           // packed V frags, 2 MB

  proj_kernel<<<dim3(256), dim3(256), 0, stream>>>(x, Wq, Wk, Wv, Qb, Kb, Vp);
  attn_kernel<<<dim3(512), dim3(512), 0, stream>>>(Qb, Kb, Vp, out);
}